// Round 14
// baseline (474.376 us; speedup 1.0000x reference)
//
#include <hip/hip_runtime.h>

#define N_NODES 50000
#define NPAD 50048            // padded row count (multiple of 128)
#define FEAT 256
#define HID 64
#define NEDGE 800000
#define SCAN_CHUNK 2048
#define NB_SCAN 25            // ceil(50000/2048)
#define NB_EDGE 3125          // NEDGE/256
#define NB_GEMM 391           // NPAD/128

typedef unsigned short bf16_t;
typedef __attribute__((ext_vector_type(8))) short bf16x8;   // 8 bf16 = 4 VGPR
typedef __attribute__((ext_vector_type(4))) float f32x4;

#define MFMA_BF16 __builtin_amdgcn_mfma_f32_16x16x32_bf16

__device__ __forceinline__ bf16_t f2bf(float f) {
    union { float f; unsigned u; } v; v.f = f;
    unsigned r = v.u + 0x7fff + ((v.u >> 16) & 1);   // RNE
    return (bf16_t)(r >> 16);
}
__device__ __forceinline__ void unpack2(unsigned u, float& lo, float& hi) {
    union { unsigned u; float f; } a, b;
    a.u = u << 16; b.u = u & 0xffff0000u;
    lo = a.f; hi = b.f;
}
__device__ __forceinline__ unsigned pack2(float lo, float hi) {
    return ((unsigned)f2bf(lo)) | (((unsigned)f2bf(hi)) << 16);
}

// ---------------- fused prep: hist (blocks 0..3124) ∥ pack_we (8) ∥ pack_wc (14) ----------------
__device__ __forceinline__ void pack_w_body(const float* __restrict__ wsrc,
        bf16_t* __restrict__ wdst, int idx) {
    int lane = idx & 63, nt = (idx >> 6) & 3, ks = idx >> 8;
    int kb  = ks * 32 + ((lane >> 4) * 8);
    int col = nt * 16 + (lane & 15);
    unsigned p[4];
#pragma unroll
    for (int j = 0; j < 4; ++j)
        p[j] = pack2(wsrc[(size_t)(kb + 2*j) * 64 + col],
                     wsrc[(size_t)(kb + 2*j + 1) * 64 + col]);
    uint4 u; u.x = p[0]; u.y = p[1]; u.z = p[2]; u.w = p[3];
    *(uint4*)(wdst + (size_t)idx * 8) = u;
}

__global__ __launch_bounds__(256) void prep_kernel(const int* __restrict__ rows,
        int* __restrict__ cnt, const float* __restrict__ we, bf16_t* __restrict__ wep,
        const float* __restrict__ wc, bf16_t* __restrict__ wcp) {
    const int b = blockIdx.x, t = threadIdx.x;
    if (b < NB_EDGE) {
        int e = b * 256 + t;
        if (e < NEDGE) atomicAdd(&cnt[rows[e]], 1);
    } else if (b < NB_EDGE + 8) {
        pack_w_body(we, wep, (b - NB_EDGE) * 256 + t);
    } else {
        pack_w_body(wc, wcp, (b - NB_EDGE - 8) * 256 + t);
    }
}

// ---------------- scans ----------------
__global__ __launch_bounds__(256) void scan_a(const int* __restrict__ cnt,
        int* __restrict__ bsum) {
    __shared__ int sd[256];
    const int t = threadIdx.x;
    const int base = blockIdx.x * SCAN_CHUNK + t * 8;
    int s = 0;
#pragma unroll
    for (int i = 0; i < 8; ++i) {
        int idx = base + i;
        s += (idx < N_NODES) ? cnt[idx] : 0;
    }
    sd[t] = s; __syncthreads();
    for (int off = 128; off > 0; off >>= 1) {
        if (t < off) sd[t] += sd[t + off];
        __syncthreads();
    }
    if (t == 0) bsum[blockIdx.x] = sd[0];
}

__global__ __launch_bounds__(256) void scan_c(const int* __restrict__ cnt,
        const int* __restrict__ bsum, int* __restrict__ rowPtr,
        int* __restrict__ fill) {
    __shared__ int sd[256];
    __shared__ int sboff;
    const int t = threadIdx.x;
    const int base = blockIdx.x * SCAN_CHUNK + t * 8;
    if (t == 0) {
        int a = 0, tot = 0;
        for (int b = 0; b < NB_SCAN; ++b) {
            int v = bsum[b];
            if (b < (int)blockIdx.x) a += v;
            tot += v;
        }
        sboff = a;
        if (blockIdx.x == NB_SCAN - 1) rowPtr[N_NODES] = tot;
    }
    int v[8];
    int s = 0;
#pragma unroll
    for (int i = 0; i < 8; ++i) {
        int idx = base + i;
        v[i] = (idx < N_NODES) ? cnt[idx] : 0;
        s += v[i];
    }
    sd[t] = s; __syncthreads();
    for (int off = 1; off < 256; off <<= 1) {
        int add = (t >= off) ? sd[t - off] : 0;
        __syncthreads();
        sd[t] += add;
        __syncthreads();
    }
    int run = sboff + (sd[t] - s);
#pragma unroll
    for (int i = 0; i < 8; ++i) {
        int idx = base + i;
        if (idx < N_NODES) { rowPtr[idx] = run; fill[idx] = 0; }
        run += v[i];
    }
}

// ---------------- fused scatter (blocks 0..3124) ∥ embed_mfma (blocks 3125..3515) ----------------
__global__ __launch_bounds__(256) void scatter_embed_kernel(
        const int* __restrict__ rows, const int* __restrict__ cols,
        const float* __restrict__ vals, const int* __restrict__ rowPtr,
        int* __restrict__ fill, uint2* __restrict__ colval,
        const float* __restrict__ x, const bf16_t* __restrict__ wep,
        bf16_t* __restrict__ r0) {
    if (blockIdx.x < NB_EDGE) {
        int e = blockIdx.x * 256 + threadIdx.x;
        if (e < NEDGE) {
            int r = rows[e];
            int p = rowPtr[r] + atomicAdd(&fill[r], 1);
            uint2 cv; cv.x = (unsigned)cols[e]; cv.y = __float_as_uint(vals[e]);
            colval[p] = cv;
        }
        return;
    }
    // ---- embed body ----
    const int blk = blockIdx.x - NB_EDGE;
    const int t = threadIdx.x;
    const int l = t & 63, w = t >> 6;
    const int lm = l & 15, lg = l >> 4;
    const int base = blk * 128 + w * 32;

    int m0 = base + lm, m1 = base + 16 + lm;
    if (m0 >= N_NODES) m0 = N_NODES - 1;
    if (m1 >= N_NODES) m1 = N_NODES - 1;
    const float* xp0 = x + (size_t)m0 * FEAT + lg * 8;
    const float* xp1 = x + (size_t)m1 * FEAT + lg * 8;

    f32x4 acc[2][4];
#pragma unroll
    for (int i = 0; i < 2; ++i)
#pragma unroll
        for (int j = 0; j < 4; ++j) acc[i][j] = (f32x4){0.f, 0.f, 0.f, 0.f};

    auto aload = [&](const float* p) {
        float4 u0 = *(const float4*)(p);
        float4 u1 = *(const float4*)(p + 4);
        bf16x8 r;
        r[0] = (short)f2bf(u0.x); r[1] = (short)f2bf(u0.y);
        r[2] = (short)f2bf(u0.z); r[3] = (short)f2bf(u0.w);
        r[4] = (short)f2bf(u1.x); r[5] = (short)f2bf(u1.y);
        r[6] = (short)f2bf(u1.z); r[7] = (short)f2bf(u1.w);
        return r;
    };
    auto wb = [&](int ks, int nt) {
        return *(const bf16x8*)(wep + ((size_t)(ks * 4 + nt) * 64 + l) * 8);
    };

    const int NK = FEAT / 32;  // 8
    bf16x8 a0 = aload(xp0), a1 = aload(xp1);
    bf16x8 b0 = wb(0,0), b1 = wb(0,1), b2 = wb(0,2), b3 = wb(0,3);
    for (int ks = 0; ks < NK; ++ks) {
        bf16x8 na0, na1, nb0, nb1, nb2, nb3;
        const bool more = (ks + 1 < NK);
        if (more) {
            int kt = (ks + 1) * 32;
            na0 = aload(xp0 + kt); na1 = aload(xp1 + kt);
            nb0 = wb(ks+1,0); nb1 = wb(ks+1,1); nb2 = wb(ks+1,2); nb3 = wb(ks+1,3);
        }
        acc[0][0] = MFMA_BF16(a0, b0, acc[0][0], 0, 0, 0);
        acc[1][0] = MFMA_BF16(a1, b0, acc[1][0], 0, 0, 0);
        acc[0][1] = MFMA_BF16(a0, b1, acc[0][1], 0, 0, 0);
        acc[1][1] = MFMA_BF16(a1, b1, acc[1][1], 0, 0, 0);
        acc[0][2] = MFMA_BF16(a0, b2, acc[0][2], 0, 0, 0);
        acc[1][2] = MFMA_BF16(a1, b2, acc[1][2], 0, 0, 0);
        acc[0][3] = MFMA_BF16(a0, b3, acc[0][3], 0, 0, 0);
        acc[1][3] = MFMA_BF16(a1, b3, acc[1][3], 0, 0, 0);
        if (more) { a0 = na0; a1 = na1; b0 = nb0; b1 = nb1; b2 = nb2; b3 = nb3; }
    }

#pragma unroll
    for (int rt = 0; rt < 2; ++rt)
#pragma unroll
        for (int r = 0; r < 4; ++r) {
            int R = base + rt * 16 + lg * 4 + r;
            if (R < N_NODES) {
                bf16_t* o = r0 + (size_t)R * HID + lm;
                o[0]  = f2bf(fmaxf(acc[rt][0][r], 0.f));
                o[16] = f2bf(fmaxf(acc[rt][1][r], 0.f));
                o[32] = f2bf(fmaxf(acc[rt][2][r], 0.f));
                o[48] = f2bf(fmaxf(acc[rt][3][r], 0.f));
            }
        }
}

// ---------------- SpMM w64: pair-lane (2 edges / gather instr, 16 edges / batch) ----------------
__global__ __launch_bounds__(256) void spmm64_kernel(const uint2* __restrict__ colval,
        const int* __restrict__ rowPtr,
        const bf16_t* __restrict__ src, bf16_t* __restrict__ dst) {
    const int l = threadIdx.x & 63;
    const int c = l & 31, h = l >> 5;           // c = uint feature-pair, h = edge parity
    const int row  = (int)((blockIdx.x * 256u + threadIdx.x) >> 6);
    const int beg = rowPtr[row], end = rowPtr[row + 1];
    const unsigned* srcu = (const unsigned*)src;  // row stride 32 uints
    float a0 = 0.f, a1 = 0.f;
    int i = beg;
    for (; i + 16 <= end; i += 16) {
        uint2 cv[8]; unsigned g[8];
#pragma unroll
        for (int j = 0; j < 8; ++j) cv[j] = colval[i + 2*j + h];
#pragma unroll
        for (int j = 0; j < 8; ++j) g[j] = srcu[(size_t)cv[j].x * 32 + c];
#pragma unroll
        for (int j = 0; j < 8; ++j) {
            float lo, hi; unpack2(g[j], lo, hi);
            float v = __uint_as_float(cv[j].y);
            a0 += v*lo; a1 += v*hi;
        }
    }
    for (; i + 2 <= end; i += 2) {
        uint2 cv = colval[i + h];
        float lo, hi; unpack2(srcu[(size_t)cv.x*32 + c], lo, hi);
        float v = __uint_as_float(cv.y);
        a0 += v*lo; a1 += v*hi;
    }
    if (i + h < end) {   // odd leftover edge: h==0 half only
        uint2 cv = colval[i + h];
        float lo, hi; unpack2(srcu[(size_t)cv.x*32 + c], lo, hi);
        float v = __uint_as_float(cv.y);
        a0 += v*lo; a1 += v*hi;
    }
    a0 += __shfl_xor(a0, 32);
    a1 += __shfl_xor(a1, 32);
    if (h == 0)
        ((unsigned*)dst)[(size_t)row*32 + c] = pack2(a0, a1);
}

// t = adj@s fused with r1cat = relu(concat[s-r0, t-s-r0])
__global__ __launch_bounds__(256) void spmm64f_kernel(const uint2* __restrict__ colval,
        const int* __restrict__ rowPtr,
        const bf16_t* __restrict__ s, const bf16_t* __restrict__ r0,
        bf16_t* __restrict__ r1c) {
    const int l = threadIdx.x & 63;
    const int c = l & 31, h = l >> 5;
    const int row  = (int)((blockIdx.x * 256u + threadIdx.x) >> 6);
    const int beg = rowPtr[row], end = rowPtr[row + 1];
    const unsigned* su = (const unsigned*)s;      // row stride 32 uints
    const unsigned* r0u = (const unsigned*)r0;
    float a0 = 0.f, a1 = 0.f;
    int i = beg;
    for (; i + 16 <= end; i += 16) {
        uint2 cv[8]; unsigned g[8];
#pragma unroll
        for (int j = 0; j < 8; ++j) cv[j] = colval[i + 2*j + h];
#pragma unroll
        for (int j = 0; j < 8; ++j) g[j] = su[(size_t)cv[j].x * 32 + c];
#pragma unroll
        for (int j = 0; j < 8; ++j) {
            float lo, hi; unpack2(g[j], lo, hi);
            float v = __uint_as_float(cv[j].y);
            a0 += v*lo; a1 += v*hi;
        }
    }
    for (; i + 2 <= end; i += 2) {
        uint2 cv = colval[i + h];
        float lo, hi; unpack2(su[(size_t)cv.x*32 + c], lo, hi);
        float v = __uint_as_float(cv.y);
        a0 += v*lo; a1 += v*hi;
    }
    if (i + h < end) {
        uint2 cv = colval[i + h];
        float lo, hi; unpack2(su[(size_t)cv.x*32 + c], lo, hi);
        float v = __uint_as_float(cv.y);
        a0 += v*lo; a1 += v*hi;
    }
    a0 += __shfl_xor(a0, 32);
    a1 += __shfl_xor(a1, 32);
    if (h == 0) {
        float sv0, sv1, rv0, rv1;
        unpack2(su[(size_t)row*32 + c], sv0, sv1);
        unpack2(r0u[(size_t)row*32 + c], rv0, rv1);
        unsigned* r1u = (unsigned*)r1c;  // row stride 64 uints
        r1u[(size_t)row*64 + c]      = pack2(fmaxf(sv0 - rv0, 0.f), fmaxf(sv1 - rv1, 0.f));
        r1u[(size_t)row*64 + 32 + c] = pack2(fmaxf(a0 - sv0 - rv0, 0.f), fmaxf(a1 - sv1 - rv1, 0.f));
    }
}

// ---------------- SpMM w128: pair-lane uint2 (2 edges / gather instr, 16 / batch) ----------------
__global__ __launch_bounds__(256) void spmm128_kernel(const uint2* __restrict__ colval,
        const int* __restrict__ rowPtr,
        const bf16_t* __restrict__ src, bf16_t* __restrict__ dst) {
    const int l = threadIdx.x & 63;
    const int c = l & 31, h = l >> 5;           // c = uint2 quad-feature idx, h = edge parity
    const int row  = (int)((blockIdx.x * 256u + threadIdx.x) >> 6);
    const int beg = rowPtr[row], end = rowPtr[row + 1];
    const uint2* srcu = (const uint2*)src;      // row stride 32 uint2 (256 B)
    float a0 = 0.f, a1 = 0.f, a2 = 0.f, a3 = 0.f;
    int i = beg;
    for (; i + 16 <= end; i += 16) {
        uint2 cv[8]; uint2 g[8];
#pragma unroll
        for (int j = 0; j < 8; ++j) cv[j] = colval[i + 2*j + h];
#pragma unroll
        for (int j = 0; j < 8; ++j) g[j] = srcu[(size_t)cv[j].x * 32 + c];
#pragma unroll
        for (int j = 0; j < 8; ++j) {
            float v = __uint_as_float(cv[j].y);
            float lo, hi;
            unpack2(g[j].x, lo, hi); a0 += v*lo; a1 += v*hi;
            unpack2(g[j].y, lo, hi); a2 += v*lo; a3 += v*hi;
        }
    }
    for (; i + 2 <= end; i += 2) {
        uint2 cv = colval[i + h];
        uint2 g = srcu[(size_t)cv.x*32 + c];
        float v = __uint_as_float(cv.y);
        float lo, hi;
        unpack2(g.x, lo, hi); a0 += v*lo; a1 += v*hi;
        unpack2(g.y, lo, hi); a2 += v*lo; a3 += v*hi;
    }
    if (i + h < end) {
        uint2 cv = colval[i + h];
        uint2 g = srcu[(size_t)cv.x*32 + c];
        float v = __uint_as_float(cv.y);
        float lo, hi;
        unpack2(g.x, lo, hi); a0 += v*lo; a1 += v*hi;
        unpack2(g.y, lo, hi); a2 += v*lo; a3 += v*hi;
    }
    a0 += __shfl_xor(a0, 32);
    a1 += __shfl_xor(a1, 32);
    a2 += __shfl_xor(a2, 32);
    a3 += __shfl_xor(a3, 32);
    if (h == 0) {
        uint2 o; o.x = pack2(a0, a1); o.y = pack2(a2, a3);
        ((uint2*)dst)[(size_t)row*32 + c] = o;
    }
}

__global__ __launch_bounds__(256) void spmm128f_kernel(const uint2* __restrict__ colval,
        const int* __restrict__ rowPtr,
        const bf16_t* __restrict__ s2, const bf16_t* __restrict__ r1,
        bf16_t* __restrict__ r2c) {
    const int l = threadIdx.x & 63;
    const int c = l & 31, h = l >> 5;
    const int row  = (int)((blockIdx.x * 256u + threadIdx.x) >> 6);
    const int beg = rowPtr[row], end = rowPtr[row + 1];
    const uint2* s2u = (const uint2*)s2;        // row stride 32 uint2
    const uint2* r1u = (const uint2*)r1;
    float a0 = 0.f, a1 = 0.f, a2 = 0.f, a3 = 0.f;
    int i = beg;
    for (; i + 16 <= end; i += 16) {
        uint2 cv[8]; uint2 g[8];
#pragma unroll
        for (int j = 0; j < 8; ++j) cv[j] = colval[i + 2*j + h];
#pragma unroll
        for (int j = 0; j < 8; ++j) g[j] = s2u[(size_t)cv[j].x * 32 + c];
#pragma unroll
        for (int j = 0; j < 8; ++j) {
            float v = __uint_as_float(cv[j].y);
            float lo, hi;
            unpack2(g[j].x, lo, hi); a0 += v*lo; a1 += v*hi;
            unpack2(g[j].y, lo, hi); a2 += v*lo; a3 += v*hi;
        }
    }
    for (; i + 2 <= end; i += 2) {
        uint2 cv = colval[i + h];
        uint2 g = s2u[(size_t)cv.x*32 + c];
        float v = __uint_as_float(cv.y);
        float lo, hi;
        unpack2(g.x, lo, hi); a0 += v*lo; a1 += v*hi;
        unpack2(g.y, lo, hi); a2 += v*lo; a3 += v*hi;
    }
    if (i + h < end) {
        uint2 cv = colval[i + h];
        uint2 g = s2u[(size_t)cv.x*32 + c];
        float v = __uint_as_float(cv.y);
        float lo, hi;
        unpack2(g.x, lo, hi); a0 += v*lo; a1 += v*hi;
        unpack2(g.y, lo, hi); a2 += v*lo; a3 += v*hi;
    }
    a0 += __shfl_xor(a0, 32);
    a1 += __shfl_xor(a1, 32);
    a2 += __shfl_xor(a2, 32);
    a3 += __shfl_xor(a3, 32);
    if (h == 0) {
        uint2 us = s2u[(size_t)row*32 + c];
        uint2 ur = r1u[(size_t)row*32 + c];
        float s0v, s1v, s2v, s3v, r0v, r1v, r2v, r3v;
        unpack2(us.x, s0v, s1v); unpack2(us.y, s2v, s3v);
        unpack2(ur.x, r0v, r1v); unpack2(ur.y, r2v, r3v);
        uint2* r2u = (uint2*)r2c;  // row stride 64 uint2
        uint2 oA, oB;
        oA.x = pack2(fmaxf(s0v - r0v, 0.f), fmaxf(s1v - r1v, 0.f));
        oA.y = pack2(fmaxf(s2v - r2v, 0.f), fmaxf(s3v - r3v, 0.f));
        oB.x = pack2(fmaxf(a0 - s0v - r0v, 0.f), fmaxf(a1 - s1v - r1v, 0.f));
        oB.y = pack2(fmaxf(a2 - s2v - r2v, 0.f), fmaxf(a3 - s3v - r3v, 0.f));
        r2u[(size_t)row*64 + c]      = oA;
        r2u[(size_t)row*64 + 32 + c] = oB;
    }
}

// ---------------- classify (MFMA) + softmax ----------------
__global__ __launch_bounds__(256) void classify_mfma(const bf16_t* __restrict__ r0,
        const bf16_t* __restrict__ r1, const bf16_t* __restrict__ r2,
        const bf16_t* __restrict__ wcp, float* __restrict__ out) {
    const int t = threadIdx.x;
    const int l = t & 63, w = t >> 6;
    const int lm = l & 15, lg = l >> 4;
    const int base = blockIdx.x * 128 + w * 32;

    const int m0 = base + lm, m1 = base + 16 + lm;   // padded buffers: reads safe
    const bf16_t* p0_r0 = r0 + (size_t)m0 * 64  + lg * 8;
    const bf16_t* p0_r1 = r1 + (size_t)m0 * 128 + lg * 8;
    const bf16_t* p0_r2 = r2 + (size_t)m0 * 256 + lg * 8;
    const bf16_t* p1_r0 = r0 + (size_t)m1 * 64  + lg * 8;
    const bf16_t* p1_r1 = r1 + (size_t)m1 * 128 + lg * 8;
    const bf16_t* p1_r2 = r2 + (size_t)m1 * 256 + lg * 8;

    f32x4 acc[2][4];
#pragma unroll
    for (int i = 0; i < 2; ++i)
#pragma unroll
        for (int j = 0; j < 4; ++j) acc[i][j] = (f32x4){0.f, 0.f, 0.f, 0.f};

    auto aload = [&](const bf16_t* pr0, const bf16_t* pr1, const bf16_t* pr2, int kt) {
        const bf16_t* p = (kt < 64) ? (pr0 + kt) : (kt < 192) ? (pr1 + kt - 64) : (pr2 + kt - 192);
        return *(const bf16x8*)p;
    };
    auto wb = [&](int ks, int nt) {
        return *(const bf16x8*)(wcp + ((size_t)(ks * 4 + nt) * 64 + l) * 8);
    };

    const int NK = 14;  // 448/32
    bf16x8 a0 = aload(p0_r0, p0_r1, p0_r2, 0);
    bf16x8 a1 = aload(p1_r0, p1_r1, p1_r2, 0);
    bf16x8 b0 = wb(0,0), b1 = wb(0,1), b2 = wb(0,2), b3 = wb(0,3);
    for (int ks = 0; ks < NK; ++ks) {
        bf16x8 na0, na1, nb0, nb1, nb2, nb3;
        const bool more = (ks + 1 < NK);
        if (more) {
            int kt = (ks + 1) * 32;
            na0 = aload(p0_r0, p0_r1, p0_r2, kt);
            na1 = aload(p1_r0, p1_r1, p1_r2, kt);
            nb0 = wb(ks+1,0); nb1 = wb(ks+1,1); nb2 = wb(ks+1,2); nb3 = wb(ks+1,3);
        }
        acc[0][0] = MFMA_BF16(a0, b0, acc[0][0], 0, 0, 0);
        acc[1][0] = MFMA_BF16(a1, b0, acc[1][0], 0, 0, 0);
        acc[0][1] = MFMA_BF16(a0, b1, acc[0][1], 0, 0, 0);
        acc[1][1] = MFMA_BF16(a1, b1, acc[1][1], 0, 0, 0);
        acc[0][2] = MFMA_BF16(a0, b2, acc[0][2], 0, 0, 0);
        acc[1][2] = MFMA_BF16(a1, b2, acc[1][2], 0, 0, 0);
        acc[0][3] = MFMA_BF16(a0, b3, acc[0][3], 0, 0, 0);
        acc[1][3] = MFMA_BF16(a1, b3, acc[1][3], 0, 0, 0);
        if (more) { a0 = na0; a1 = na1; b0 = nb0; b1 = nb1; b2 = nb2; b3 = nb3; }
    }

#pragma unroll
    for (int rt = 0; rt < 2; ++rt)
#pragma unroll
        for (int r = 0; r < 4; ++r) {
            float v0 = acc[rt][0][r], v1 = acc[rt][1][r];
            float v2 = acc[rt][2][r], v3 = acc[rt][3][r];
            float m = fmaxf(fmaxf(v0, v1), fmaxf(v2, v3));
#pragma unroll
            for (int o = 1; o < 16; o <<= 1) m = fmaxf(m, __shfl_xor(m, o));
            float e0 = __expf(v0 - m), e1 = __expf(v1 - m);
            float e2 = __expf(v2 - m), e3 = __expf(v3 - m);
            float s = e0 + e1 + e2 + e3;
#pragma unroll
            for (int o = 1; o < 16; o <<= 1) s += __shfl_xor(s, o);
            float inv = 1.f / s;
            int R = base + rt * 16 + lg * 4 + r;
            if (R < N_NODES) {
                float* o = out + (size_t)R * 64 + lm;
                o[0]  = e0 * inv;
                o[16] = e1 * inv;
                o[32] = e2 * inv;
                o[48] = e3 * inv;
            }
        }
}

extern "C" void kernel_launch(void* const* d_in, const int* in_sizes, int n_in,
                              void* d_out, int out_size, void* d_ws, size_t ws_size,
                              hipStream_t stream) {
    const float* x    = (const float*)d_in[0];
    const int*   erow = (const int*)d_in[1];
    const int*   ecol = (const int*)d_in[2];
    const float* eval = (const float*)d_in[3];
    const float* we   = (const float*)d_in[4];
    const float* wc   = (const float*)d_in[5];
    float* out = (float*)d_out;

    char* wsp = (char*)d_ws;
    size_t off = 0;
    auto take = [&](size_t bytes) {
        char* p = wsp + off;
        off += (bytes + 255) & ~(size_t)255;
        return p;
    };
    bf16_t* r0     = (bf16_t*)take((size_t)NPAD * 64 * 2);
    bf16_t* sbuf   = (bf16_t*)take((size_t)NPAD * 128 * 2);  // s (w64) then s2 (w128)
    bf16_t* r1c    = (bf16_t*)take((size_t)NPAD * 128 * 2);
    bf16_t* r2c    = (bf16_t*)take((size_t)NPAD * 256 * 2);
    int*    cnt    = (int*)take((size_t)N_NODES * 4);
    int*    rowPtr = (int*)take((size_t)(N_NODES + 1) * 4);
    int*    fill   = (int*)take((size_t)N_NODES * 4);
    int*    bsum   = (int*)take((size_t)NB_SCAN * 4);
    uint2*  colval = (uint2*)take((size_t)NEDGE * 8);
    bf16_t* wep    = (bf16_t*)take((size_t)8  * 256 * 8 * 2);   // 8 ksteps packed We
    bf16_t* wcp    = (bf16_t*)take((size_t)14 * 256 * 8 * 2);   // 14 ksteps packed Wc
    (void)ws_size; (void)in_sizes; (void)n_in; (void)out_size;

    hipMemsetAsync(cnt, 0, (size_t)N_NODES * 4, stream);

    // hist ∥ pack_we ∥ pack_wc
    prep_kernel<<<NB_EDGE + 8 + 14, 256, 0, stream>>>(erow, cnt, we, wep, wc, wcp);
    scan_a<<<NB_SCAN, 256, 0, stream>>>(cnt, bsum);
    scan_c<<<NB_SCAN, 256, 0, stream>>>(cnt, bsum, rowPtr, fill);   // also zeroes fill
    // scatter ∥ embed
    scatter_embed_kernel<<<NB_EDGE + NB_GEMM, 256, 0, stream>>>(
        erow, ecol, eval, rowPtr, fill, colval, x, wep, r0);

    spmm64_kernel <<<12500, 256, 0, stream>>>(colval, rowPtr, r0, sbuf);
    spmm64f_kernel<<<12500, 256, 0, stream>>>(colval, rowPtr, sbuf, r0, r1c);
    spmm128_kernel<<<12500, 256, 0, stream>>>(colval, rowPtr, r1c, sbuf);
    spmm128f_kernel<<<12500, 256, 0, stream>>>(colval, rowPtr, sbuf, r1c, r2c);

    classify_mfma<<<NB_GEMM, 256, 0, stream>>>(r0, r1c, r2c, wcp, out);
}

// Round 15
// 303.105 us; speedup vs baseline: 1.5651x; 1.5651x over previous
//
#include <hip/hip_runtime.h>

#define N_NODES 50000
#define NPAD 50048            // padded row count (multiple of 128)
#define FEAT 256
#define HID 64
#define NEDGE 800000
#define SCAN_CHUNK 2048
#define NB_SCAN 25            // ceil(50000/2048)
#define NB_EDGE 3125          // NEDGE/256
#define NB_GEMM 391           // NPAD/128
#define NBKT_FINE 12500       // ceil(50000/4)   fine buckets (row>>2)
#define RPB 128               // rows per csr-sort block
#define NBKT_CSR 391          // ceil(50000/128)

typedef unsigned short bf16_t;
typedef __attribute__((ext_vector_type(8))) short bf16x8;   // 8 bf16 = 4 VGPR
typedef __attribute__((ext_vector_type(4))) float f32x4;

#define MFMA_BF16 __builtin_amdgcn_mfma_f32_16x16x32_bf16

__device__ __forceinline__ bf16_t f2bf(float f) {
    union { float f; unsigned u; } v; v.f = f;
    unsigned r = v.u + 0x7fff + ((v.u >> 16) & 1);   // RNE
    return (bf16_t)(r >> 16);
}
__device__ __forceinline__ void unpack2(unsigned u, float& lo, float& hi) {
    union { unsigned u; float f; } a, b;
    a.u = u << 16; b.u = u & 0xffff0000u;
    lo = a.f; hi = b.f;
}
__device__ __forceinline__ unsigned pack2(float lo, float hi) {
    return ((unsigned)f2bf(lo)) | (((unsigned)f2bf(hi)) << 16);
}

// ---------------- fused prep: hist (blocks 0..3124) ∥ pack_we (8) ∥ pack_wc (14) ----------------
__device__ __forceinline__ void pack_w_body(const float* __restrict__ wsrc,
        bf16_t* __restrict__ wdst, int idx) {
    int lane = idx & 63, nt = (idx >> 6) & 3, ks = idx >> 8;
    int kb  = ks * 32 + ((lane >> 4) * 8);
    int col = nt * 16 + (lane & 15);
    unsigned p[4];
#pragma unroll
    for (int j = 0; j < 4; ++j)
        p[j] = pack2(wsrc[(size_t)(kb + 2*j) * 64 + col],
                     wsrc[(size_t)(kb + 2*j + 1) * 64 + col]);
    uint4 u; u.x = p[0]; u.y = p[1]; u.z = p[2]; u.w = p[3];
    *(uint4*)(wdst + (size_t)idx * 8) = u;
}

__global__ __launch_bounds__(256) void prep_kernel(const int* __restrict__ rows,
        int* __restrict__ cnt, const float* __restrict__ we, bf16_t* __restrict__ wep,
        const float* __restrict__ wc, bf16_t* __restrict__ wcp) {
    const int b = blockIdx.x, t = threadIdx.x;
    if (b < NB_EDGE) {
        int e = b * 256 + t;
        if (e < NEDGE) atomicAdd(&cnt[rows[e]], 1);
    } else if (b < NB_EDGE + 8) {
        pack_w_body(we, wep, (b - NB_EDGE) * 256 + t);
    } else {
        pack_w_body(wc, wcp, (b - NB_EDGE - 8) * 256 + t);
    }
}

// ---------------- scans ----------------
__global__ __launch_bounds__(256) void scan_a(const int* __restrict__ cnt,
        int* __restrict__ bsum) {
    __shared__ int sd[256];
    const int t = threadIdx.x;
    const int base = blockIdx.x * SCAN_CHUNK + t * 8;
    int s = 0;
#pragma unroll
    for (int i = 0; i < 8; ++i) {
        int idx = base + i;
        s += (idx < N_NODES) ? cnt[idx] : 0;
    }
    sd[t] = s; __syncthreads();
    for (int off = 128; off > 0; off >>= 1) {
        if (t < off) sd[t] += sd[t + off];
        __syncthreads();
    }
    if (t == 0) bsum[blockIdx.x] = sd[0];
}

// scan_c derives block offset (and rowPtr[N]) inline; also zeroes bfill.
__global__ __launch_bounds__(256) void scan_c(const int* __restrict__ cnt,
        const int* __restrict__ bsum, int* __restrict__ rowPtr,
        int* __restrict__ bfill) {
    __shared__ int sd[256];
    __shared__ int sboff;
    const int t = threadIdx.x;
    const int base = blockIdx.x * SCAN_CHUNK + t * 8;
    if (t == 0) {
        int a = 0, tot = 0;
        for (int b = 0; b < NB_SCAN; ++b) {
            int v = bsum[b];
            if (b < (int)blockIdx.x) a += v;
            tot += v;
        }
        sboff = a;
        if (blockIdx.x == NB_SCAN - 1) rowPtr[N_NODES] = tot;
    }
    int v[8];
    int s = 0;
#pragma unroll
    for (int i = 0; i < 8; ++i) {
        int idx = base + i;
        v[i] = (idx < N_NODES) ? cnt[idx] : 0;
        s += v[i];
    }
    sd[t] = s; __syncthreads();
    for (int off = 1; off < 256; off <<= 1) {
        int add = (t >= off) ? sd[t - off] : 0;
        __syncthreads();
        sd[t] += add;
        __syncthreads();
    }
    int run = sboff + (sd[t] - s);
#pragma unroll
    for (int i = 0; i < 8; ++i) {
        int idx = base + i;
        if (idx < N_NODES) {
            rowPtr[idx] = run;
            if (idx < NBKT_FINE) bfill[idx] = 0;
        }
        run += v[i];
    }
}

// ---------------- fused bin (blocks 0..3124) ∥ embed_mfma (blocks 3125..3515) ----------------
// bin: bucket = row>>2 (12500 buckets, ~64 edges each). Writes land in 512B
// bucket windows -> ~8 edges per 64B line (vs 1 for per-row scatter).
__global__ __launch_bounds__(256) void bin_embed_kernel(
        const int* __restrict__ rows, const int* __restrict__ cols,
        const float* __restrict__ vals, const int* __restrict__ rowPtr,
        int* __restrict__ bfill, int* __restrict__ tmpR, uint2* __restrict__ tmpCV,
        const float* __restrict__ x, const bf16_t* __restrict__ wep,
        bf16_t* __restrict__ r0) {
    if (blockIdx.x < NB_EDGE) {
        int e = blockIdx.x * 256 + threadIdx.x;
        if (e < NEDGE) {
            int r = rows[e];
            int b = r >> 2;
            int p = rowPtr[b << 2] + atomicAdd(&bfill[b], 1);
            tmpR[p] = r;
            uint2 cv; cv.x = (unsigned)cols[e]; cv.y = __float_as_uint(vals[e]);
            tmpCV[p] = cv;
        }
        return;
    }
    // ---- embed body ----
    const int blk = blockIdx.x - NB_EDGE;
    const int t = threadIdx.x;
    const int l = t & 63, w = t >> 6;
    const int lm = l & 15, lg = l >> 4;
    const int base = blk * 128 + w * 32;

    int m0 = base + lm, m1 = base + 16 + lm;
    if (m0 >= N_NODES) m0 = N_NODES - 1;
    if (m1 >= N_NODES) m1 = N_NODES - 1;
    const float* xp0 = x + (size_t)m0 * FEAT + lg * 8;
    const float* xp1 = x + (size_t)m1 * FEAT + lg * 8;

    f32x4 acc[2][4];
#pragma unroll
    for (int i = 0; i < 2; ++i)
#pragma unroll
        for (int j = 0; j < 4; ++j) acc[i][j] = (f32x4){0.f, 0.f, 0.f, 0.f};

    auto aload = [&](const float* p) {
        float4 u0 = *(const float4*)(p);
        float4 u1 = *(const float4*)(p + 4);
        bf16x8 r;
        r[0] = (short)f2bf(u0.x); r[1] = (short)f2bf(u0.y);
        r[2] = (short)f2bf(u0.z); r[3] = (short)f2bf(u0.w);
        r[4] = (short)f2bf(u1.x); r[5] = (short)f2bf(u1.y);
        r[6] = (short)f2bf(u1.z); r[7] = (short)f2bf(u1.w);
        return r;
    };
    auto wb = [&](int ks, int nt) {
        return *(const bf16x8*)(wep + ((size_t)(ks * 4 + nt) * 64 + l) * 8);
    };

    const int NK = FEAT / 32;  // 8
    bf16x8 a0 = aload(xp0), a1 = aload(xp1);
    bf16x8 b0 = wb(0,0), b1 = wb(0,1), b2 = wb(0,2), b3 = wb(0,3);
    for (int ks = 0; ks < NK; ++ks) {
        bf16x8 na0, na1, nb0, nb1, nb2, nb3;
        const bool more = (ks + 1 < NK);
        if (more) {
            int kt = (ks + 1) * 32;
            na0 = aload(xp0 + kt); na1 = aload(xp1 + kt);
            nb0 = wb(ks+1,0); nb1 = wb(ks+1,1); nb2 = wb(ks+1,2); nb3 = wb(ks+1,3);
        }
        acc[0][0] = MFMA_BF16(a0, b0, acc[0][0], 0, 0, 0);
        acc[1][0] = MFMA_BF16(a1, b0, acc[1][0], 0, 0, 0);
        acc[0][1] = MFMA_BF16(a0, b1, acc[0][1], 0, 0, 0);
        acc[1][1] = MFMA_BF16(a1, b1, acc[1][1], 0, 0, 0);
        acc[0][2] = MFMA_BF16(a0, b2, acc[0][2], 0, 0, 0);
        acc[1][2] = MFMA_BF16(a1, b2, acc[1][2], 0, 0, 0);
        acc[0][3] = MFMA_BF16(a0, b3, acc[0][3], 0, 0, 0);
        acc[1][3] = MFMA_BF16(a1, b3, acc[1][3], 0, 0, 0);
        if (more) { a0 = na0; a1 = na1; b0 = nb0; b1 = nb1; b2 = nb2; b3 = nb3; }
    }

#pragma unroll
    for (int rt = 0; rt < 2; ++rt)
#pragma unroll
        for (int r = 0; r < 4; ++r) {
            int R = base + rt * 16 + lg * 4 + r;
            if (R < N_NODES) {
                bf16_t* o = r0 + (size_t)R * HID + lm;
                o[0]  = f2bf(fmaxf(acc[rt][0][r], 0.f));
                o[16] = f2bf(fmaxf(acc[rt][1][r], 0.f));
                o[32] = f2bf(fmaxf(acc[rt][2][r], 0.f));
                o[48] = f2bf(fmaxf(acc[rt][3][r], 0.f));
            }
        }
}

// per-128-row-block exact CSR ordering; reads/writes stay in the block's
// contiguous ~16KB window (L2-resident). Verbatim R9 structure (it was fast).
__global__ __launch_bounds__(256) void bucket_csr_kernel(const int* __restrict__ rowPtr,
        const int* __restrict__ tmpR, const uint2* __restrict__ tmpCV,
        uint2* __restrict__ colval) {
    __shared__ int cnt[RPB];
    __shared__ int off[RPB];
    const int t = threadIdx.x;
    const int b = blockIdx.x;
    const int r0 = b << 7;
    const int r1 = (r0 + RPB < N_NODES) ? (r0 + RPB) : N_NODES;
    const int base = rowPtr[r0];
    const int nE = rowPtr[r1] - base;

    if (t < RPB) cnt[t] = 0;
    __syncthreads();
    for (int i = t; i < nE; i += 256)
        atomicAdd(&cnt[tmpR[base + i] - r0], 1);
    __syncthreads();
    if (t < RPB) off[t] = cnt[t];
    __syncthreads();
    for (int d = 1; d < RPB; d <<= 1) {
        int v = 0;
        if (t < RPB && t >= d) v = off[t - d];
        __syncthreads();
        if (t < RPB) off[t] += v;
        __syncthreads();
    }
    if (t < RPB) off[t] -= cnt[t];   // exclusive
    __syncthreads();
    for (int i = t; i < nE; i += 256) {
        int r = tmpR[base + i];
        int p = atomicAdd(&off[r - r0], 1);
        colval[base + p] = tmpCV[base + i];
    }
}

// ---------------- SpMM w64: pair-lane (R13 proven) ----------------
__global__ __launch_bounds__(256) void spmm64_kernel(const uint2* __restrict__ colval,
        const int* __restrict__ rowPtr,
        const bf16_t* __restrict__ src, bf16_t* __restrict__ dst) {
    const int l = threadIdx.x & 63;
    const int c = l & 31, h = l >> 5;           // c = uint feature-pair, h = edge parity
    const int row  = (int)((blockIdx.x * 256u + threadIdx.x) >> 6);
    const int beg = rowPtr[row], end = rowPtr[row + 1];
    const unsigned* srcu = (const unsigned*)src;  // row stride 32 uints
    float a0 = 0.f, a1 = 0.f;
    int i = beg;
    for (; i + 16 <= end; i += 16) {
        uint2 cv[8]; unsigned g[8];
#pragma unroll
        for (int j = 0; j < 8; ++j) cv[j] = colval[i + 2*j + h];
#pragma unroll
        for (int j = 0; j < 8; ++j) g[j] = srcu[(size_t)cv[j].x * 32 + c];
#pragma unroll
        for (int j = 0; j < 8; ++j) {
            float lo, hi; unpack2(g[j], lo, hi);
            float v = __uint_as_float(cv[j].y);
            a0 += v*lo; a1 += v*hi;
        }
    }
    for (; i + 2 <= end; i += 2) {
        uint2 cv = colval[i + h];
        float lo, hi; unpack2(srcu[(size_t)cv.x*32 + c], lo, hi);
        float v = __uint_as_float(cv.y);
        a0 += v*lo; a1 += v*hi;
    }
    if (i + h < end) {   // odd leftover edge: h==0 half only
        uint2 cv = colval[i + h];
        float lo, hi; unpack2(srcu[(size_t)cv.x*32 + c], lo, hi);
        float v = __uint_as_float(cv.y);
        a0 += v*lo; a1 += v*hi;
    }
    a0 += __shfl_xor(a0, 32);
    a1 += __shfl_xor(a1, 32);
    if (h == 0)
        ((unsigned*)dst)[(size_t)row*32 + c] = pack2(a0, a1);
}

// t = adj@s fused with r1cat = relu(concat[s-r0, t-s-r0])
__global__ __launch_bounds__(256) void spmm64f_kernel(const uint2* __restrict__ colval,
        const int* __restrict__ rowPtr,
        const bf16_t* __restrict__ s, const bf16_t* __restrict__ r0,
        bf16_t* __restrict__ r1c) {
    const int l = threadIdx.x & 63;
    const int c = l & 31, h = l >> 5;
    const int row  = (int)((blockIdx.x * 256u + threadIdx.x) >> 6);
    const int beg = rowPtr[row], end = rowPtr[row + 1];
    const unsigned* su = (const unsigned*)s;      // row stride 32 uints
    const unsigned* r0u = (const unsigned*)r0;
    float a0 = 0.f, a1 = 0.f;
    int i = beg;
    for (; i + 16 <= end; i += 16) {
        uint2 cv[8]; unsigned g[8];
#pragma unroll
        for (int j = 0; j < 8; ++j) cv[j] = colval[i + 2*j + h];
#pragma unroll
        for (int j = 0; j < 8; ++j) g[j] = su[(size_t)cv[j].x * 32 + c];
#pragma unroll
        for (int j = 0; j < 8; ++j) {
            float lo, hi; unpack2(g[j], lo, hi);
            float v = __uint_as_float(cv[j].y);
            a0 += v*lo; a1 += v*hi;
        }
    }
    for (; i + 2 <= end; i += 2) {
        uint2 cv = colval[i + h];
        float lo, hi; unpack2(su[(size_t)cv.x*32 + c], lo, hi);
        float v = __uint_as_float(cv.y);
        a0 += v*lo; a1 += v*hi;
    }
    if (i + h < end) {
        uint2 cv = colval[i + h];
        float lo, hi; unpack2(su[(size_t)cv.x*32 + c], lo, hi);
        float v = __uint_as_float(cv.y);
        a0 += v*lo; a1 += v*hi;
    }
    a0 += __shfl_xor(a0, 32);
    a1 += __shfl_xor(a1, 32);
    if (h == 0) {
        float sv0, sv1, rv0, rv1;
        unpack2(su[(size_t)row*32 + c], sv0, sv1);
        unpack2(r0u[(size_t)row*32 + c], rv0, rv1);
        unsigned* r1u = (unsigned*)r1c;  // row stride 64 uints
        r1u[(size_t)row*64 + c]      = pack2(fmaxf(sv0 - rv0, 0.f), fmaxf(sv1 - rv1, 0.f));
        r1u[(size_t)row*64 + 32 + c] = pack2(fmaxf(a0 - sv0 - rv0, 0.f), fmaxf(a1 - sv1 - rv1, 0.f));
    }
}

// ---------------- SpMM w128: lane-per-edge uint, batch 8 (R11/R13 proven) ----------------
__global__ __launch_bounds__(256) void spmm128_kernel(const uint2* __restrict__ colval,
        const int* __restrict__ rowPtr,
        const bf16_t* __restrict__ src, bf16_t* __restrict__ dst) {
    const int lane = threadIdx.x & 63;
    const int row  = (int)((blockIdx.x * 256u + threadIdx.x) >> 6);
    const int beg = rowPtr[row], end = rowPtr[row + 1];
    const unsigned* srcu = (const unsigned*)src;  // row stride 64 uints
    float a0 = 0.f, a1 = 0.f;
    int i = beg;
    for (; i + 8 <= end; i += 8) {
        uint2 cv[8]; unsigned u[8];
#pragma unroll
        for (int j = 0; j < 8; ++j) cv[j] = colval[i+j];
#pragma unroll
        for (int j = 0; j < 8; ++j) u[j] = srcu[(size_t)cv[j].x*64 + lane];
#pragma unroll
        for (int j = 0; j < 8; ++j) {
            float lo, hi; unpack2(u[j], lo, hi);
            float v = __uint_as_float(cv[j].y);
            a0 += v*lo; a1 += v*hi;
        }
    }
    for (; i < end; ++i) {
        uint2 cv = colval[i];
        float lo, hi; unpack2(srcu[(size_t)cv.x*64 + lane], lo, hi);
        float v = __uint_as_float(cv.y);
        a0 += v*lo; a1 += v*hi;
    }
    ((unsigned*)dst)[(size_t)row*64 + lane] = pack2(a0, a1);
}

__global__ __launch_bounds__(256) void spmm128f_kernel(const uint2* __restrict__ colval,
        const int* __restrict__ rowPtr,
        const bf16_t* __restrict__ s2, const bf16_t* __restrict__ r1,
        bf16_t* __restrict__ r2c) {
    const int lane = threadIdx.x & 63;
    const int row  = (int)((blockIdx.x * 256u + threadIdx.x) >> 6);
    const int beg = rowPtr[row], end = rowPtr[row + 1];
    const unsigned* s2u = (const unsigned*)s2;
    const unsigned* r1u = (const unsigned*)r1;
    float a0 = 0.f, a1 = 0.f;
    int i = beg;
    for (; i + 8 <= end; i += 8) {
        uint2 cv[8]; unsigned u[8];
#pragma unroll
        for (int j = 0; j < 8; ++j) cv[j] = colval[i+j];
#pragma unroll
        for (int j = 0; j < 8; ++j) u[j] = s2u[(size_t)cv[j].x*64 + lane];
#pragma unroll
        for (int j = 0; j < 8; ++j) {
            float lo, hi; unpack2(u[j], lo, hi);
            float v = __uint_as_float(cv[j].y);
            a0 += v*lo; a1 += v*hi;
        }
    }
    for (; i < end; ++i) {
        uint2 cv = colval[i];
        float lo, hi; unpack2(s2u[(size_t)cv.x*64 + lane], lo, hi);
        float v = __uint_as_float(cv.y);
        a0 += v*lo; a1 += v*hi;
    }
    float s0v, s1v, r0v, r1v;
    unpack2(s2u[(size_t)row*64 + lane], s0v, s1v);
    unpack2(r1u[(size_t)row*64 + lane], r0v, r1v);
    unsigned* r2u = (unsigned*)r2c;  // row stride 128 uints
    r2u[(size_t)row*128 + lane]      = pack2(fmaxf(s0v - r0v, 0.f), fmaxf(s1v - r1v, 0.f));
    r2u[(size_t)row*128 + 64 + lane] = pack2(fmaxf(a0 - s0v - r0v, 0.f), fmaxf(a1 - s1v - r1v, 0.f));
}

// ---------------- classify (MFMA) + softmax ----------------
__global__ __launch_bounds__(256) void classify_mfma(const bf16_t* __restrict__ r0,
        const bf16_t* __restrict__ r1, const bf16_t* __restrict__ r2,
        const bf16_t* __restrict__ wcp, float* __restrict__ out) {
    const int t = threadIdx.x;
    const int l = t & 63, w = t >> 6;
    const int lm = l & 15, lg = l >> 4;
    const int base = blockIdx.x * 128 + w * 32;

    const int m0 = base + lm, m1 = base + 16 + lm;   // padded buffers: reads safe
    const bf16_t* p0_r0 = r0 + (size_t)m0 * 64  + lg * 8;
    const bf16_t* p0_r1 = r1 + (size_t)m0 * 128 + lg * 8;
    const bf16_t* p0_r2 = r2 + (size_t)m0 * 256 + lg * 8;
    const bf16_t* p1_r0 = r0 + (size_t)m1 * 64  + lg * 8;
    const bf16_t* p1_r1 = r1 + (size_t)m1 * 128 + lg * 8;
    const bf16_t* p1_r2 = r2 + (size_t)m1 * 256 + lg * 8;

    f32x4 acc[2][4];
#pragma unroll
    for (int i = 0; i < 2; ++i)
#pragma unroll
        for (int j = 0; j < 4; ++j) acc[i][j] = (f32x4){0.f, 0.f, 0.f, 0.f};

    auto aload = [&](const bf16_t* pr0, const bf16_t* pr1, const bf16_t* pr2, int kt) {
        const bf16_t* p = (kt < 64) ? (pr0 + kt) : (kt < 192) ? (pr1 + kt - 64) : (pr2 + kt - 192);
        return *(const bf16x8*)p;
    };
    auto wb = [&](int ks, int nt) {
        return *(const bf16x8*)(wcp + ((size_t)(ks * 4 + nt) * 64 + l) * 8);
    };

    const int NK = 14;  // 448/32
    bf16x8 a0 = aload(p0_r0, p0_r1, p0_r2, 0);
    bf16x8 a1 = aload(p1_r0, p1_r1, p1_r2, 0);
    bf16x8 b0 = wb(0,0), b1 = wb(0,1), b2 = wb(0,2), b3 = wb(0,3);
    for (int ks = 0; ks < NK; ++ks) {
        bf16x8 na0, na1, nb0, nb1, nb2, nb3;
        const bool more = (ks + 1 < NK);
        if (more) {
            int kt = (ks + 1) * 32;
            na0 = aload(p0_r0, p0_r1, p0_r2, kt);
            na1 = aload(p1_r0, p1_r1, p1_r2, kt);
            nb0 = wb(ks+1,0); nb1 = wb(ks+1,1); nb2 = wb(ks+1,2); nb3 = wb(ks+1,3);
        }
        acc[0][0] = MFMA_BF16(a0, b0, acc[0][0], 0, 0, 0);
        acc[1][0] = MFMA_BF16(a1, b0, acc[1][0], 0, 0, 0);
        acc[0][1] = MFMA_BF16(a0, b1, acc[0][1], 0, 0, 0);
        acc[1][1] = MFMA_BF16(a1, b1, acc[1][1], 0, 0, 0);
        acc[0][2] = MFMA_BF16(a0, b2, acc[0][2], 0, 0, 0);
        acc[1][2] = MFMA_BF16(a1, b2, acc[1][2], 0, 0, 0);
        acc[0][3] = MFMA_BF16(a0, b3, acc[0][3], 0, 0, 0);
        acc[1][3] = MFMA_BF16(a1, b3, acc[1][3], 0, 0, 0);
        if (more) { a0 = na0; a1 = na1; b0 = nb0; b1 = nb1; b2 = nb2; b3 = nb3; }
    }

#pragma unroll
    for (int rt = 0; rt < 2; ++rt)
#pragma unroll
        for (int r = 0; r < 4; ++r) {
            float v0 = acc[rt][0][r], v1 = acc[rt][1][r];
            float v2 = acc[rt][2][r], v3 = acc[rt][3][r];
            float m = fmaxf(fmaxf(v0, v1), fmaxf(v2, v3));
#pragma unroll
            for (int o = 1; o < 16; o <<= 1) m = fmaxf(m, __shfl_xor(m, o));
            float e0 = __expf(v0 - m), e1 = __expf(v1 - m);
            float e2 = __expf(v2 - m), e3 = __expf(v3 - m);
            float s = e0 + e1 + e2 + e3;
#pragma unroll
            for (int o = 1; o < 16; o <<= 1) s += __shfl_xor(s, o);
            float inv = 1.f / s;
            int R = base + rt * 16 + lg * 4 + r;
            if (R < N_NODES) {
                float* o = out + (size_t)R * 64 + lm;
                o[0]  = e0 * inv;
                o[16] = e1 * inv;
                o[32] = e2 * inv;
                o[48] = e3 * inv;
            }
        }
}

extern "C" void kernel_launch(void* const* d_in, const int* in_sizes, int n_in,
                              void* d_out, int out_size, void* d_ws, size_t ws_size,
                              hipStream_t stream) {
    const float* x    = (const float*)d_in[0];
    const int*   erow = (const int*)d_in[1];
    const int*   ecol = (const int*)d_in[2];
    const float* eval = (const float*)d_in[3];
    const float* we   = (const float*)d_in[4];
    const float* wc   = (const float*)d_in[5];
    float* out = (float*)d_out;

    char* wsp = (char*)d_ws;
    size_t off = 0;
    auto take = [&](size_t bytes) {
        char* p = wsp + off;
        off += (bytes + 255) & ~(size_t)255;
        return p;
    };
    bf16_t* r0     = (bf16_t*)take((size_t)NPAD * 64 * 2);
    bf16_t* sbuf   = (bf16_t*)take((size_t)NPAD * 128 * 2);  // s (w64) then s2 (w128)
    bf16_t* r1c    = (bf16_t*)take((size_t)NPAD * 128 * 2);
    bf16_t* r2c    = (bf16_t*)take((size_t)NPAD * 256 * 2);
    int*    cnt    = (int*)take((size_t)N_NODES * 4);
    int*    rowPtr = (int*)take((size_t)(N_NODES + 1) * 4);
    int*    bfill  = (int*)take((size_t)NBKT_FINE * 4);
    int*    bsum   = (int*)take((size_t)NB_SCAN * 4);
    uint2*  colval = (uint2*)take((size_t)NEDGE * 8);
    int*    tmpR   = (int*)take((size_t)NEDGE * 4);
    uint2*  tmpCV  = (uint2*)take((size_t)NEDGE * 8);
    bf16_t* wep    = (bf16_t*)take((size_t)8  * 256 * 8 * 2);   // 8 ksteps packed We
    bf16_t* wcp    = (bf16_t*)take((size_t)14 * 256 * 8 * 2);   // 14 ksteps packed Wc
    (void)ws_size; (void)in_sizes; (void)n_in; (void)out_size;

    hipMemsetAsync(cnt, 0, (size_t)N_NODES * 4, stream);

    // hist ∥ pack_we ∥ pack_wc
    prep_kernel<<<NB_EDGE + 8 + 14, 256, 0, stream>>>(erow, cnt, we, wep, wc, wcp);
    scan_a<<<NB_SCAN, 256, 0, stream>>>(cnt, bsum);
    scan_c<<<NB_SCAN, 256, 0, stream>>>(cnt, bsum, rowPtr, bfill);  // also zeroes bfill
    // fine-bucket bin ∥ embed
    bin_embed_kernel<<<NB_EDGE + NB_GEMM, 256, 0, stream>>>(
        erow, ecol, eval, rowPtr, bfill, tmpR, tmpCV, x, wep, r0);
    bucket_csr_kernel<<<NBKT_CSR, 256, 0, stream>>>(rowPtr, tmpR, tmpCV, colval);

    spmm64_kernel <<<12500, 256, 0, stream>>>(colval, rowPtr, r0, sbuf);
    spmm64f_kernel<<<12500, 256, 0, stream>>>(colval, rowPtr, sbuf, r0, r1c);
    spmm128_kernel<<<12500, 256, 0, stream>>>(colval, rowPtr, r1c, sbuf);
    spmm128f_kernel<<<12500, 256, 0, stream>>>(colval, rowPtr, sbuf, r1c, r2c);

    classify_mfma<<<NB_GEMM, 256, 0, stream>>>(r0, r1c, r2c, wcp, out);
}

// Round 16
// 271.735 us; speedup vs baseline: 1.7457x; 1.1154x over previous
//
#include <hip/hip_runtime.h>

#define N_NODES 50000
#define NPAD 50048            // padded row count (multiple of 128)
#define FEAT 256
#define HID 64
#define NEDGE 800000
#define SCAN_CHUNK 2048
#define NB_SCAN 25            // ceil(50000/2048)
#define NB_EDGE 3125          // NEDGE/256
#define NB_GEMM 391           // NPAD/128

typedef unsigned short bf16_t;
typedef __attribute__((ext_vector_type(8))) short bf16x8;   // 8 bf16 = 4 VGPR
typedef __attribute__((ext_vector_type(4))) float f32x4;

#define MFMA_BF16 __builtin_amdgcn_mfma_f32_16x16x32_bf16

__device__ __forceinline__ bf16_t f2bf(float f) {
    union { float f; unsigned u; } v; v.f = f;
    unsigned r = v.u + 0x7fff + ((v.u >> 16) & 1);   // RNE
    return (bf16_t)(r >> 16);
}
__device__ __forceinline__ void unpack2(unsigned u, float& lo, float& hi) {
    union { unsigned u; float f; } a, b;
    a.u = u << 16; b.u = u & 0xffff0000u;
    lo = a.f; hi = b.f;
}
__device__ __forceinline__ unsigned pack2(float lo, float hi) {
    return ((unsigned)f2bf(lo)) | (((unsigned)f2bf(hi)) << 16);
}

// ---------------- fused prep: hist (blocks 0..3124) ∥ pack_we (8) ∥ pack_wc (14) ----------------
__device__ __forceinline__ void pack_w_body(const float* __restrict__ wsrc,
        bf16_t* __restrict__ wdst, int idx) {
    int lane = idx & 63, nt = (idx >> 6) & 3, ks = idx >> 8;
    int kb  = ks * 32 + ((lane >> 4) * 8);
    int col = nt * 16 + (lane & 15);
    unsigned p[4];
#pragma unroll
    for (int j = 0; j < 4; ++j)
        p[j] = pack2(wsrc[(size_t)(kb + 2*j) * 64 + col],
                     wsrc[(size_t)(kb + 2*j + 1) * 64 + col]);
    uint4 u; u.x = p[0]; u.y = p[1]; u.z = p[2]; u.w = p[3];
    *(uint4*)(wdst + (size_t)idx * 8) = u;
}

__global__ __launch_bounds__(256) void prep_kernel(const int* __restrict__ rows,
        int* __restrict__ cnt, const float* __restrict__ we, bf16_t* __restrict__ wep,
        const float* __restrict__ wc, bf16_t* __restrict__ wcp) {
    const int b = blockIdx.x, t = threadIdx.x;
    if (b < NB_EDGE) {
        int e = b * 256 + t;
        if (e < NEDGE) atomicAdd(&cnt[rows[e]], 1);
    } else if (b < NB_EDGE + 8) {
        pack_w_body(we, wep, (b - NB_EDGE) * 256 + t);
    } else {
        pack_w_body(wc, wcp, (b - NB_EDGE - 8) * 256 + t);
    }
}

// ---------------- scans ----------------
__global__ __launch_bounds__(256) void scan_a(const int* __restrict__ cnt,
        int* __restrict__ bsum) {
    __shared__ int sd[256];
    const int t = threadIdx.x;
    const int base = blockIdx.x * SCAN_CHUNK + t * 8;
    int s = 0;
#pragma unroll
    for (int i = 0; i < 8; ++i) {
        int idx = base + i;
        s += (idx < N_NODES) ? cnt[idx] : 0;
    }
    sd[t] = s; __syncthreads();
    for (int off = 128; off > 0; off >>= 1) {
        if (t < off) sd[t] += sd[t + off];
        __syncthreads();
    }
    if (t == 0) bsum[blockIdx.x] = sd[0];
}

__global__ __launch_bounds__(256) void scan_c(const int* __restrict__ cnt,
        const int* __restrict__ bsum, int* __restrict__ rowPtr,
        int* __restrict__ fill) {
    __shared__ int sd[256];
    __shared__ int sboff;
    const int t = threadIdx.x;
    const int base = blockIdx.x * SCAN_CHUNK + t * 8;
    if (t == 0) {
        int a = 0, tot = 0;
        for (int b = 0; b < NB_SCAN; ++b) {
            int v = bsum[b];
            if (b < (int)blockIdx.x) a += v;
            tot += v;
        }
        sboff = a;
        if (blockIdx.x == NB_SCAN - 1) rowPtr[N_NODES] = tot;
    }
    int v[8];
    int s = 0;
#pragma unroll
    for (int i = 0; i < 8; ++i) {
        int idx = base + i;
        v[i] = (idx < N_NODES) ? cnt[idx] : 0;
        s += v[i];
    }
    sd[t] = s; __syncthreads();
    for (int off = 1; off < 256; off <<= 1) {
        int add = (t >= off) ? sd[t - off] : 0;
        __syncthreads();
        sd[t] += add;
        __syncthreads();
    }
    int run = sboff + (sd[t] - s);
#pragma unroll
    for (int i = 0; i < 8; ++i) {
        int idx = base + i;
        if (idx < N_NODES) { rowPtr[idx] = run; fill[idx] = 0; }
        run += v[i];
    }
}

// ---------------- fused scatter (blocks 0..3124) ∥ embed_mfma (blocks 3125..3515) ----------------
__global__ __launch_bounds__(256) void scatter_embed_kernel(
        const int* __restrict__ rows, const int* __restrict__ cols,
        const float* __restrict__ vals, const int* __restrict__ rowPtr,
        int* __restrict__ fill, uint2* __restrict__ colval,
        const float* __restrict__ x, const bf16_t* __restrict__ wep,
        bf16_t* __restrict__ r0) {
    if (blockIdx.x < NB_EDGE) {
        int e = blockIdx.x * 256 + threadIdx.x;
        if (e < NEDGE) {
            int r = rows[e];
            int p = rowPtr[r] + atomicAdd(&fill[r], 1);
            uint2 cv; cv.x = (unsigned)cols[e]; cv.y = __float_as_uint(vals[e]);
            colval[p] = cv;
        }
        return;
    }
    // ---- embed body ----
    const int blk = blockIdx.x - NB_EDGE;
    const int t = threadIdx.x;
    const int l = t & 63, w = t >> 6;
    const int lm = l & 15, lg = l >> 4;
    const int base = blk * 128 + w * 32;

    int m0 = base + lm, m1 = base + 16 + lm;
    if (m0 >= N_NODES) m0 = N_NODES - 1;
    if (m1 >= N_NODES) m1 = N_NODES - 1;
    const float* xp0 = x + (size_t)m0 * FEAT + lg * 8;
    const float* xp1 = x + (size_t)m1 * FEAT + lg * 8;

    f32x4 acc[2][4];
#pragma unroll
    for (int i = 0; i < 2; ++i)
#pragma unroll
        for (int j = 0; j < 4; ++j) acc[i][j] = (f32x4){0.f, 0.f, 0.f, 0.f};

    auto aload = [&](const float* p) {
        float4 u0 = *(const float4*)(p);
        float4 u1 = *(const float4*)(p + 4);
        bf16x8 r;
        r[0] = (short)f2bf(u0.x); r[1] = (short)f2bf(u0.y);
        r[2] = (short)f2bf(u0.z); r[3] = (short)f2bf(u0.w);
        r[4] = (short)f2bf(u1.x); r[5] = (short)f2bf(u1.y);
        r[6] = (short)f2bf(u1.z); r[7] = (short)f2bf(u1.w);
        return r;
    };
    auto wb = [&](int ks, int nt) {
        return *(const bf16x8*)(wep + ((size_t)(ks * 4 + nt) * 64 + l) * 8);
    };

    const int NK = FEAT / 32;  // 8
    bf16x8 a0 = aload(xp0), a1 = aload(xp1);
    bf16x8 b0 = wb(0,0), b1 = wb(0,1), b2 = wb(0,2), b3 = wb(0,3);
    for (int ks = 0; ks < NK; ++ks) {
        bf16x8 na0, na1, nb0, nb1, nb2, nb3;
        const bool more = (ks + 1 < NK);
        if (more) {
            int kt = (ks + 1) * 32;
            na0 = aload(xp0 + kt); na1 = aload(xp1 + kt);
            nb0 = wb(ks+1,0); nb1 = wb(ks+1,1); nb2 = wb(ks+1,2); nb3 = wb(ks+1,3);
        }
        acc[0][0] = MFMA_BF16(a0, b0, acc[0][0], 0, 0, 0);
        acc[1][0] = MFMA_BF16(a1, b0, acc[1][0], 0, 0, 0);
        acc[0][1] = MFMA_BF16(a0, b1, acc[0][1], 0, 0, 0);
        acc[1][1] = MFMA_BF16(a1, b1, acc[1][1], 0, 0, 0);
        acc[0][2] = MFMA_BF16(a0, b2, acc[0][2], 0, 0, 0);
        acc[1][2] = MFMA_BF16(a1, b2, acc[1][2], 0, 0, 0);
        acc[0][3] = MFMA_BF16(a0, b3, acc[0][3], 0, 0, 0);
        acc[1][3] = MFMA_BF16(a1, b3, acc[1][3], 0, 0, 0);
        if (more) { a0 = na0; a1 = na1; b0 = nb0; b1 = nb1; b2 = nb2; b3 = nb3; }
    }

#pragma unroll
    for (int rt = 0; rt < 2; ++rt)
#pragma unroll
        for (int r = 0; r < 4; ++r) {
            int R = base + rt * 16 + lg * 4 + r;
            if (R < N_NODES) {
                bf16_t* o = r0 + (size_t)R * HID + lm;
                o[0]  = f2bf(fmaxf(acc[rt][0][r], 0.f));
                o[16] = f2bf(fmaxf(acc[rt][1][r], 0.f));
                o[32] = f2bf(fmaxf(acc[rt][2][r], 0.f));
                o[48] = f2bf(fmaxf(acc[rt][3][r], 0.f));
            }
        }
}

// ---------------- SpMM w64: pair-lane (R13 proven) ----------------
__global__ __launch_bounds__(256) void spmm64_kernel(const uint2* __restrict__ colval,
        const int* __restrict__ rowPtr,
        const bf16_t* __restrict__ src, bf16_t* __restrict__ dst) {
    const int l = threadIdx.x & 63;
    const int c = l & 31, h = l >> 5;           // c = uint feature-pair, h = edge parity
    const int row  = (int)((blockIdx.x * 256u + threadIdx.x) >> 6);
    const int beg = rowPtr[row], end = rowPtr[row + 1];
    const unsigned* srcu = (const unsigned*)src;  // row stride 32 uints
    float a0 = 0.f, a1 = 0.f;
    int i = beg;
    for (; i + 16 <= end; i += 16) {
        uint2 cv[8]; unsigned g[8];
#pragma unroll
        for (int j = 0; j < 8; ++j) cv[j] = colval[i + 2*j + h];
#pragma unroll
        for (int j = 0; j < 8; ++j) g[j] = srcu[(size_t)cv[j].x * 32 + c];
#pragma unroll
        for (int j = 0; j < 8; ++j) {
            float lo, hi; unpack2(g[j], lo, hi);
            float v = __uint_as_float(cv[j].y);
            a0 += v*lo; a1 += v*hi;
        }
    }
    for (; i + 2 <= end; i += 2) {
        uint2 cv = colval[i + h];
        float lo, hi; unpack2(srcu[(size_t)cv.x*32 + c], lo, hi);
        float v = __uint_as_float(cv.y);
        a0 += v*lo; a1 += v*hi;
    }
    if (i + h < end) {   // odd leftover edge: h==0 half only
        uint2 cv = colval[i + h];
        float lo, hi; unpack2(srcu[(size_t)cv.x*32 + c], lo, hi);
        float v = __uint_as_float(cv.y);
        a0 += v*lo; a1 += v*hi;
    }
    a0 += __shfl_xor(a0, 32);
    a1 += __shfl_xor(a1, 32);
    if (h == 0)
        ((unsigned*)dst)[(size_t)row*32 + c] = pack2(a0, a1);
}

// t = adj@s fused with r1cat = relu(concat[s-r0, t-s-r0])
__global__ __launch_bounds__(256) void spmm64f_kernel(const uint2* __restrict__ colval,
        const int* __restrict__ rowPtr,
        const bf16_t* __restrict__ s, const bf16_t* __restrict__ r0,
        bf16_t* __restrict__ r1c) {
    const int l = threadIdx.x & 63;
    const int c = l & 31, h = l >> 5;
    const int row  = (int)((blockIdx.x * 256u + threadIdx.x) >> 6);
    const int beg = rowPtr[row], end = rowPtr[row + 1];
    const unsigned* su = (const unsigned*)s;      // row stride 32 uints
    const unsigned* r0u = (const unsigned*)r0;
    float a0 = 0.f, a1 = 0.f;
    int i = beg;
    for (; i + 16 <= end; i += 16) {
        uint2 cv[8]; unsigned g[8];
#pragma unroll
        for (int j = 0; j < 8; ++j) cv[j] = colval[i + 2*j + h];
#pragma unroll
        for (int j = 0; j < 8; ++j) g[j] = su[(size_t)cv[j].x * 32 + c];
#pragma unroll
        for (int j = 0; j < 8; ++j) {
            float lo, hi; unpack2(g[j], lo, hi);
            float v = __uint_as_float(cv[j].y);
            a0 += v*lo; a1 += v*hi;
        }
    }
    for (; i + 2 <= end; i += 2) {
        uint2 cv = colval[i + h];
        float lo, hi; unpack2(su[(size_t)cv.x*32 + c], lo, hi);
        float v = __uint_as_float(cv.y);
        a0 += v*lo; a1 += v*hi;
    }
    if (i + h < end) {
        uint2 cv = colval[i + h];
        float lo, hi; unpack2(su[(size_t)cv.x*32 + c], lo, hi);
        float v = __uint_as_float(cv.y);
        a0 += v*lo; a1 += v*hi;
    }
    a0 += __shfl_xor(a0, 32);
    a1 += __shfl_xor(a1, 32);
    if (h == 0) {
        float sv0, sv1, rv0, rv1;
        unpack2(su[(size_t)row*32 + c], sv0, sv1);
        unpack2(r0u[(size_t)row*32 + c], rv0, rv1);
        unsigned* r1u = (unsigned*)r1c;  // row stride 64 uints
        r1u[(size_t)row*64 + c]      = pack2(fmaxf(sv0 - rv0, 0.f), fmaxf(sv1 - rv1, 0.f));
        r1u[(size_t)row*64 + 32 + c] = pack2(fmaxf(a0 - sv0 - rv0, 0.f), fmaxf(a1 - sv1 - rv1, 0.f));
    }
}

// ---------------- SpMM w128: lane-per-edge uint, 16-deep batch + 8 + serial tail ----------------
__global__ __launch_bounds__(256) void spmm128_kernel(const uint2* __restrict__ colval,
        const int* __restrict__ rowPtr,
        const bf16_t* __restrict__ src, bf16_t* __restrict__ dst) {
    const int lane = threadIdx.x & 63;
    const int row  = (int)((blockIdx.x * 256u + threadIdx.x) >> 6);
    const int beg = rowPtr[row], end = rowPtr[row + 1];
    const unsigned* srcu = (const unsigned*)src;  // row stride 64 uints
    float a0 = 0.f, a1 = 0.f;
    int i = beg;
    for (; i + 16 <= end; i += 16) {
        uint2 cv[16]; unsigned u[16];
#pragma unroll
        for (int j = 0; j < 16; ++j) cv[j] = colval[i+j];
#pragma unroll
        for (int j = 0; j < 16; ++j) u[j] = srcu[(size_t)cv[j].x*64 + lane];
#pragma unroll
        for (int j = 0; j < 16; ++j) {
            float lo, hi; unpack2(u[j], lo, hi);
            float v = __uint_as_float(cv[j].y);
            a0 += v*lo; a1 += v*hi;
        }
    }
    for (; i + 8 <= end; i += 8) {
        uint2 cv[8]; unsigned u[8];
#pragma unroll
        for (int j = 0; j < 8; ++j) cv[j] = colval[i+j];
#pragma unroll
        for (int j = 0; j < 8; ++j) u[j] = srcu[(size_t)cv[j].x*64 + lane];
#pragma unroll
        for (int j = 0; j < 8; ++j) {
            float lo, hi; unpack2(u[j], lo, hi);
            float v = __uint_as_float(cv[j].y);
            a0 += v*lo; a1 += v*hi;
        }
    }
    for (; i < end; ++i) {
        uint2 cv = colval[i];
        float lo, hi; unpack2(srcu[(size_t)cv.x*64 + lane], lo, hi);
        float v = __uint_as_float(cv.y);
        a0 += v*lo; a1 += v*hi;
    }
    ((unsigned*)dst)[(size_t)row*64 + lane] = pack2(a0, a1);
}

__global__ __launch_bounds__(256) void spmm128f_kernel(const uint2* __restrict__ colval,
        const int* __restrict__ rowPtr,
        const bf16_t* __restrict__ s2, const bf16_t* __restrict__ r1,
        bf16_t* __restrict__ r2c) {
    const int lane = threadIdx.x & 63;
    const int row  = (int)((blockIdx.x * 256u + threadIdx.x) >> 6);
    const int beg = rowPtr[row], end = rowPtr[row + 1];
    const unsigned* s2u = (const unsigned*)s2;
    const unsigned* r1u = (const unsigned*)r1;
    float a0 = 0.f, a1 = 0.f;
    int i = beg;
    for (; i + 16 <= end; i += 16) {
        uint2 cv[16]; unsigned u[16];
#pragma unroll
        for (int j = 0; j < 16; ++j) cv[j] = colval[i+j];
#pragma unroll
        for (int j = 0; j < 16; ++j) u[j] = s2u[(size_t)cv[j].x*64 + lane];
#pragma unroll
        for (int j = 0; j < 16; ++j) {
            float lo, hi; unpack2(u[j], lo, hi);
            float v = __uint_as_float(cv[j].y);
            a0 += v*lo; a1 += v*hi;
        }
    }
    for (; i + 8 <= end; i += 8) {
        uint2 cv[8]; unsigned u[8];
#pragma unroll
        for (int j = 0; j < 8; ++j) cv[j] = colval[i+j];
#pragma unroll
        for (int j = 0; j < 8; ++j) u[j] = s2u[(size_t)cv[j].x*64 + lane];
#pragma unroll
        for (int j = 0; j < 8; ++j) {
            float lo, hi; unpack2(u[j], lo, hi);
            float v = __uint_as_float(cv[j].y);
            a0 += v*lo; a1 += v*hi;
        }
    }
    for (; i < end; ++i) {
        uint2 cv = colval[i];
        float lo, hi; unpack2(s2u[(size_t)cv.x*64 + lane], lo, hi);
        float v = __uint_as_float(cv.y);
        a0 += v*lo; a1 += v*hi;
    }
    float s0v, s1v, r0v, r1v;
    unpack2(s2u[(size_t)row*64 + lane], s0v, s1v);
    unpack2(r1u[(size_t)row*64 + lane], r0v, r1v);
    unsigned* r2u = (unsigned*)r2c;  // row stride 128 uints
    r2u[(size_t)row*128 + lane]      = pack2(fmaxf(s0v - r0v, 0.f), fmaxf(s1v - r1v, 0.f));
    r2u[(size_t)row*128 + 64 + lane] = pack2(fmaxf(a0 - s0v - r0v, 0.f), fmaxf(a1 - s1v - r1v, 0.f));
}

// ---------------- classify (MFMA) + softmax ----------------
__global__ __launch_bounds__(256) void classify_mfma(const bf16_t* __restrict__ r0,
        const bf16_t* __restrict__ r1, const bf16_t* __restrict__ r2,
        const bf16_t* __restrict__ wcp, float* __restrict__ out) {
    const int t = threadIdx.x;
    const int l = t & 63, w = t >> 6;
    const int lm = l & 15, lg = l >> 4;
    const int base = blockIdx.x * 128 + w * 32;

    const int m0 = base + lm, m1 = base + 16 + lm;   // padded buffers: reads safe
    const bf16_t* p0_r0 = r0 + (size_t)m0 * 64  + lg * 8;
    const bf16_t* p0_r1 = r1 + (size_t)m0 * 128 + lg * 8;
    const bf16_t* p0_r2 = r2 + (size_t)m0 * 256 + lg * 8;
    const bf16_t* p1_r0 = r0 + (size_t)m1 * 64  + lg * 8;
    const bf16_t* p1_r1 = r1 + (size_t)m1 * 128 + lg * 8;
    const bf16_t* p1_r2 = r2 + (size_t)m1 * 256 + lg * 8;

    f32x4 acc[2][4];
#pragma unroll
    for (int i = 0; i < 2; ++i)
#pragma unroll
        for (int j = 0; j < 4; ++j) acc[i][j] = (f32x4){0.f, 0.f, 0.f, 0.f};

    auto aload = [&](const bf16_t* pr0, const bf16_t* pr1, const bf16_t* pr2, int kt) {
        const bf16_t* p = (kt < 64) ? (pr0 + kt) : (kt < 192) ? (pr1 + kt - 64) : (pr2 + kt - 192);
        return *(const bf16x8*)p;
    };
    auto wb = [&](int ks, int nt) {
        return *(const bf16x8*)(wcp + ((size_t)(ks * 4 + nt) * 64 + l) * 8);
    };

    const int NK = 14;  // 448/32
    bf16x8 a0 = aload(p0_r0, p0_r1, p0_r2, 0);
    bf16x8 a1 = aload(p1_r0, p1_r1, p1_r2, 0);
    bf16x8 b0 = wb(0,0), b1 = wb(0,1), b2 = wb(0,2), b3 = wb(0,3);
    for (int ks = 0; ks < NK; ++ks) {
        bf16x8 na0, na1, nb0, nb1, nb2, nb3;
        const bool more = (ks + 1 < NK);
        if (more) {
            int kt = (ks + 1) * 32;
            na0 = aload(p0_r0, p0_r1, p0_r2, kt);
            na1 = aload(p1_r0, p1_r1, p1_r2, kt);
            nb0 = wb(ks+1,0); nb1 = wb(ks+1,1); nb2 = wb(ks+1,2); nb3 = wb(ks+1,3);
        }
        acc[0][0] = MFMA_BF16(a0, b0, acc[0][0], 0, 0, 0);
        acc[1][0] = MFMA_BF16(a1, b0, acc[1][0], 0, 0, 0);
        acc[0][1] = MFMA_BF16(a0, b1, acc[0][1], 0, 0, 0);
        acc[1][1] = MFMA_BF16(a1, b1, acc[1][1], 0, 0, 0);
        acc[0][2] = MFMA_BF16(a0, b2, acc[0][2], 0, 0, 0);
        acc[1][2] = MFMA_BF16(a1, b2, acc[1][2], 0, 0, 0);
        acc[0][3] = MFMA_BF16(a0, b3, acc[0][3], 0, 0, 0);
        acc[1][3] = MFMA_BF16(a1, b3, acc[1][3], 0, 0, 0);
        if (more) { a0 = na0; a1 = na1; b0 = nb0; b1 = nb1; b2 = nb2; b3 = nb3; }
    }

#pragma unroll
    for (int rt = 0; rt < 2; ++rt)
#pragma unroll
        for (int r = 0; r < 4; ++r) {
            float v0 = acc[rt][0][r], v1 = acc[rt][1][r];
            float v2 = acc[rt][2][r], v3 = acc[rt][3][r];
            float m = fmaxf(fmaxf(v0, v1), fmaxf(v2, v3));
#pragma unroll
            for (int o = 1; o < 16; o <<= 1) m = fmaxf(m, __shfl_xor(m, o));
            float e0 = __expf(v0 - m), e1 = __expf(v1 - m);
            float e2 = __expf(v2 - m), e3 = __expf(v3 - m);
            float s = e0 + e1 + e2 + e3;
#pragma unroll
            for (int o = 1; o < 16; o <<= 1) s += __shfl_xor(s, o);
            float inv = 1.f / s;
            int R = base + rt * 16 + lg * 4 + r;
            if (R < N_NODES) {
                float* o = out + (size_t)R * 64 + lm;
                o[0]  = e0 * inv;
                o[16] = e1 * inv;
                o[32] = e2 * inv;
                o[48] = e3 * inv;
            }
        }
}

extern "C" void kernel_launch(void* const* d_in, const int* in_sizes, int n_in,
                              void* d_out, int out_size, void* d_ws, size_t ws_size,
                              hipStream_t stream) {
    const float* x    = (const float*)d_in[0];
    const int*   erow = (const int*)d_in[1];
    const int*   ecol = (const int*)d_in[2];
    const float* eval = (const float*)d_in[3];
    const float* we   = (const float*)d_in[4];
    const float* wc   = (const float*)d_in[5];
    float* out = (float*)d_out;

    char* wsp = (char*)d_ws;
    size_t off = 0;
    auto take = [&](size_t bytes) {
        char* p = wsp + off;
        off += (bytes + 255) & ~(size_t)255;
        return p;
    };
    bf16_t* r0     = (bf16_t*)take((size_t)NPAD * 64 * 2);
    bf16_t* sbuf   = (bf16_t*)take((size_t)NPAD * 128 * 2);  // s (w64) then s2 (w128)
    bf16_t* r1c    = (bf16_t*)take((size_t)NPAD * 128 * 2);
    bf16_t* r2c    = (bf16_t*)take((size_t)NPAD * 256 * 2);
    int*    cnt    = (int*)take((size_t)N_NODES * 4);
    int*    rowPtr = (int*)take((size_t)(N_NODES + 1) * 4);
    int*    fill   = (int*)take((size_t)N_NODES * 4);
    int*    bsum   = (int*)take((size_t)NB_SCAN * 4);
    uint2*  colval = (uint2*)take((size_t)NEDGE * 8);
    bf16_t* wep    = (bf16_t*)take((size_t)8  * 256 * 8 * 2);   // 8 ksteps packed We
    bf16_t* wcp    = (bf16_t*)take((size_t)14 * 256 * 8 * 2);   // 14 ksteps packed Wc
    (void)ws_size; (void)in_sizes; (void)n_in; (void)out_size;

    hipMemsetAsync(cnt, 0, (size_t)N_NODES * 4, stream);

    // hist ∥ pack_we ∥ pack_wc
    prep_kernel<<<NB_EDGE + 8 + 14, 256, 0, stream>>>(erow, cnt, we, wep, wc, wcp);
    scan_a<<<NB_SCAN, 256, 0, stream>>>(cnt, bsum);
    scan_c<<<NB_SCAN, 256, 0, stream>>>(cnt, bsum, rowPtr, fill);   // also zeroes fill
    // scatter ∥ embed
    scatter_embed_kernel<<<NB_EDGE + NB_GEMM, 256, 0, stream>>>(
        erow, ecol, eval, rowPtr, fill, colval, x, wep, r0);

    spmm64_kernel <<<12500, 256, 0, stream>>>(colval, rowPtr, r0, sbuf);
    spmm64f_kernel<<<12500, 256, 0, stream>>>(colval, rowPtr, sbuf, r0, r1c);
    spmm128_kernel<<<12500, 256, 0, stream>>>(colval, rowPtr, r1c, sbuf);
    spmm128f_kernel<<<12500, 256, 0, stream>>>(colval, rowPtr, sbuf, r1c, r2c);

    classify_mfma<<<NB_GEMM, 256, 0, stream>>>(r0, r1c, r2c, wcp, out);
}